// Round 3
// baseline (576.894 us; speedup 1.0000x reference)
//
#include <hip/hip_runtime.h>

// Problem constants (fixed by the reference's setup_inputs).
constexpr int B  = 128;          // B_IMG * P * P = 32*2*2
constexpr int C  = 128;
constexpr int H  = 56, W = 56;
constexpr int HO = H + 2, WO = W + 2;        // 58 x 58
constexpr int PLANE_IN  = H * W;             // 3136
constexpr int PLANE_OUT = HO * WO;           // 3364 = 841 aligned float4
constexpr int NV4_OUT   = PLANE_OUT / 4;     // 841 = 3*256 + 73

__global__ __launch_bounds__(256) void pad2d_kernel(
    const float* __restrict__ x,
    const float* __restrict__ topW, const float* __restrict__ botW,
    const float* __restrict__ leftW, const float* __restrict__ rightW,
    const float* __restrict__ tlW,  const float* __restrict__ trW,
    const float* __restrict__ blW,  const float* __restrict__ brW,
    const int* __restrict__ np_ptr,
    float* __restrict__ out)
{
    const int plane = blockIdx.x;            // 0 .. B*C-1
    const int b   = plane >> 7;              // batch index (C = 128)
    const int c   = plane & (C - 1);         // channel
    const int tid = threadIdx.x;

    // Block-uniform zero masks (SGPR) -------------------------------------
    const int Pn = *np_ptr;                  // 2
    const int within = b % (Pn * Pn);
    const bool tz = within < Pn;
    const bool bz = within >= Pn * Pn - Pn;
    const bool lz = (b % Pn) == 0;
    const bool rz = (b % Pn) == Pn - 1;

    // Block-uniform channel weights (SGPR) --------------------------------
    const float tw = topW[c],  bw = botW[c];
    const float lw = leftW[c], rw = rightW[c];
    const float tl = tlW[c],   tr = trW[c];
    const float bl = blW[c],   br = brW[c];

    const float* __restrict__ xin = x + (size_t)plane * PLANE_IN;
    float4* __restrict__ o4 = (float4*)(out + (size_t)plane * PLANE_OUT);

    // Branch-free per-element value. Every path reduces to the uniform exact
    // form  val = zf ? 0 : wA * fmaf(sB, x[ib], x[ia])  with (ia,ib,wA,sB,zf)
    // chosen by cndmask select chains -> no control flow, so the compiler can
    // batch ALL loads of the unrolled loop and overlap their latency.
    //   interior: wA=1, sB=0            -> bit-exact copy
    //   edge:     wA=w, sB=1            -> w*(xa+xb), single-rounded add (fma
    //                                      with multiplicand 1.0 == plain add)
    //   corner:   wA=cw, sB=0           -> cw * x[corner]
    auto elem = [&](int r, int cc) -> float {
        const bool et = (r == 0),  eb = (r == HO - 1);
        const bool el = (cc == 0), er = (cc == WO - 1);
        const bool vert = et | eb, horz = el | er;
        const bool corner = vert & horz;

        int ra = et ? 0 : (eb ? H - 2 : r - 1);
        int rb = et ? 1 : (eb ? H - 1 : r - 1);
        int ca = el ? 0 : (er ? W - 2 : cc - 1);
        int cb = el ? 1 : (er ? W - 1 : cc - 1);
        // Corners read a single element, not the edge pair.
        ra = corner ? (et ? 0 : H - 1) : ra;
        ca = corner ? (el ? 0 : W - 1) : ca;

        const float ev = et ? tw : bw;               // vertical-edge weight
        const float eh = el ? lw : rw;               // horizontal-edge weight
        const float cw = et ? (el ? tl : tr) : (el ? bl : br);
        float wA = vert ? ev : (horz ? eh : 1.0f);
        wA = corner ? cw : wA;
        const float sB = ((vert | horz) & !corner) ? 1.0f : 0.0f;
        const bool zf = (et & tz) | (eb & bz) | (el & lz) | (er & rz);

        const float xa = xin[ra * W + ca];
        const float xb = xin[rb * W + cb];
        const float t  = fmaf(sB, xb, xa);
        return zf ? 0.0f : wA * t;
    };

    // One aligned float4 of output per thread-iteration; fully dirty 64B
    // granules on the write stream.
    auto emit = [&](int v) {
        const int j0 = v * 4;
        int r  = j0 / WO;                    // const divisor -> magic mul
        int cc = j0 - r * WO;
        float4 ov;
        ov.x = elem(r, cc);
        ++cc; if (cc == WO) { cc = 0; ++r; } // at most one row-wrap per float4
        ov.y = elem(r, cc);
        ++cc; if (cc == WO) { cc = 0; ++r; }
        ov.z = elem(r, cc);
        ++cc; if (cc == WO) { cc = 0; ++r; }
        ov.w = elem(r, cc);
        o4[v] = ov;
    };

    // 841 = 3*256 + 73: three uniform fully-unrolled iterations + tail.
#pragma unroll
    for (int k = 0; k < 3; ++k)
        emit(tid + k * 256);
    if (tid < NV4_OUT - 3 * 256)
        emit(tid + 3 * 256);
}

extern "C" void kernel_launch(void* const* d_in, const int* in_sizes, int n_in,
                              void* d_out, int out_size, void* d_ws, size_t ws_size,
                              hipStream_t stream) {
    const float* x      = (const float*)d_in[0];
    const float* topW   = (const float*)d_in[1];
    const float* botW   = (const float*)d_in[2];
    const float* leftW  = (const float*)d_in[3];
    const float* rightW = (const float*)d_in[4];
    const float* tlW    = (const float*)d_in[5];
    const float* trW    = (const float*)d_in[6];
    const float* blW    = (const float*)d_in[7];
    const float* brW    = (const float*)d_in[8];
    // d_in[9] = padding (fixed 1), d_in[10] = num_patches
    const int* np_ptr   = (const int*)d_in[10];
    float* out = (float*)d_out;

    pad2d_kernel<<<dim3(B * C), dim3(256), 0, stream>>>(
        x, topW, botW, leftW, rightW, tlW, trW, blW, brW, np_ptr, out);
}

// Round 4
// 456.929 us; speedup vs baseline: 1.2625x; 1.2625x over previous
//
#include <hip/hip_runtime.h>

// Problem constants (fixed by the reference's setup_inputs).
constexpr int B  = 128;          // B_IMG * P * P = 32*2*2
constexpr int C  = 128;
constexpr int H  = 56, W = 56;
constexpr int HO = H + 2, WO = W + 2;        // 58 x 58
constexpr int PLANE_IN  = H * W;             // 3136 floats = 12.544 KB
constexpr int PLANE_OUT = HO * WO;           // 3364 = 841 aligned float4
constexpr int NV4_IN    = PLANE_IN / 4;      // 784
constexpr int NV4_OUT   = PLANE_OUT / 4;     // 841

__global__ __launch_bounds__(256) void pad2d_kernel(
    const float* __restrict__ x,
    const float* __restrict__ topW, const float* __restrict__ botW,
    const float* __restrict__ leftW, const float* __restrict__ rightW,
    const float* __restrict__ tlW,  const float* __restrict__ trW,
    const float* __restrict__ blW,  const float* __restrict__ brW,
    const int* __restrict__ np_ptr,
    float* __restrict__ out)
{
    __shared__ float sx[PLANE_IN];           // whole input plane in LDS

    const int plane = blockIdx.x;            // 0 .. B*C-1
    const int b   = plane >> 7;              // batch index (C = 128)
    const int c   = plane & (C - 1);         // channel
    const int tid = threadIdx.x;

    // ---- Phase 1: branch-free, batched global->LDS staging --------------
    // (measured-good in round 2: batched float4 loads, one vmcnt window)
    {
        const float4* __restrict__ x4 = (const float4*)(x + (size_t)plane * PLANE_IN);
        float4* __restrict__ s4 = (float4*)sx;
        for (int i = tid; i < NV4_IN; i += 256)
            s4[i] = x4[i];
    }

    // Block-uniform zero masks (SGPR) -------------------------------------
    const int Pn = *np_ptr;                  // 2
    const int within = b % (Pn * Pn);
    const bool tz = within < Pn;
    const bool bz = within >= Pn * Pn - Pn;
    const bool lz = (b % Pn) == 0;
    const bool rz = (b % Pn) == Pn - 1;

    // Block-uniform channel weights (SGPR) --------------------------------
    const float tw = topW[c],  bw = botW[c];
    const float lw = leftW[c], rw = rightW[c];
    const float tl = tlW[c],   tr = trW[c];
    const float bl = blW[c],   br = brW[c];

    __syncthreads();

    float4* __restrict__ o4 = (float4*)(out + (size_t)plane * PLANE_OUT);

    // Branch-free per-element value, all reads from LDS. Uniform exact form
    //   val = zf ? 0 : wA * fmaf(sB, sx[ib], sx[ia])
    // with (ia,ib,wA,sB,zf) chosen by cndmask select chains -> no exec-mask
    // segments, so all ds_reads of an iteration batch under one lgkmcnt
    // window instead of serializing 6 divergent dependent chains.
    //   interior: wA=1, sB=0  -> 1.0f*xa, bit-exact copy
    //   edge:     wA=w, sB=1  -> w*(xa+xb); fmaf(1,xb,xa) == single-round add
    //   corner:   wA=cw, sB=0 -> cw * x[corner]   (xb unused: sB=0)
    // (math identical to round 3, which verified absmax == 0.)
    auto elem = [&](int r, int cc) -> float {
        const bool et = (r == 0),  eb = (r == HO - 1);
        const bool el = (cc == 0), er = (cc == WO - 1);
        const bool vert = et | eb, horz = el | er;
        const bool corner = vert & horz;

        int ra = et ? 0 : (eb ? H - 2 : r - 1);
        int rb = et ? 1 : (eb ? H - 1 : r - 1);
        int ca = el ? 0 : (er ? W - 2 : cc - 1);
        int cb = el ? 1 : (er ? W - 1 : cc - 1);
        // Corners read a single element, not the edge pair.
        ra = corner ? (et ? 0 : H - 1) : ra;
        ca = corner ? (el ? 0 : W - 1) : ca;

        const float ev = et ? tw : bw;               // vertical-edge weight
        const float eh = el ? lw : rw;               // horizontal-edge weight
        const float cw = et ? (el ? tl : tr) : (el ? bl : br);
        float wA = vert ? ev : (horz ? eh : 1.0f);
        wA = corner ? cw : wA;
        const float sB = ((vert | horz) & !corner) ? 1.0f : 0.0f;
        const bool zf = (et & tz) | (eb & bz) | (el & lz) | (er & rz);

        const float xa = sx[ra * W + ca];
        const float xb = sx[rb * W + cb];
        const float t  = fmaf(sB, xb, xa);
        return zf ? 0.0f : wA * t;
    };

    // ---- Phase 2: output-driven aligned float4 stores -------------------
    // Runtime-strided loop (trip count varies per tid) -> compiler CANNOT
    // fully unroll; this is the structural guard against round-3's
    // register-pressure / write-amplification pathology.
    for (int v = tid; v < NV4_OUT; v += 256) {
        const int j0 = v * 4;
        int r  = j0 / WO;                    // const divisor -> magic mul
        int cc = j0 - r * WO;
        float4 ov;
        ov.x = elem(r, cc);
        ++cc; if (cc == WO) { cc = 0; ++r; } // at most one row-wrap per float4
        ov.y = elem(r, cc);
        ++cc; if (cc == WO) { cc = 0; ++r; }
        ov.z = elem(r, cc);
        ++cc; if (cc == WO) { cc = 0; ++r; }
        ov.w = elem(r, cc);
        o4[v] = ov;
    }
}

extern "C" void kernel_launch(void* const* d_in, const int* in_sizes, int n_in,
                              void* d_out, int out_size, void* d_ws, size_t ws_size,
                              hipStream_t stream) {
    const float* x      = (const float*)d_in[0];
    const float* topW   = (const float*)d_in[1];
    const float* botW   = (const float*)d_in[2];
    const float* leftW  = (const float*)d_in[3];
    const float* rightW = (const float*)d_in[4];
    const float* tlW    = (const float*)d_in[5];
    const float* trW    = (const float*)d_in[6];
    const float* blW    = (const float*)d_in[7];
    const float* brW    = (const float*)d_in[8];
    // d_in[9] = padding (fixed 1), d_in[10] = num_patches
    const int* np_ptr   = (const int*)d_in[10];
    float* out = (float*)d_out;

    pad2d_kernel<<<dim3(B * C), dim3(256), 0, stream>>>(
        x, topW, botW, leftW, rightW, tlW, trW, blW, brW, np_ptr, out);
}